// Round 9
// baseline (351.892 us; speedup 1.0000x reference)
//
#include <hip/hip_runtime.h>
#include <hip/hip_bf16.h>
#include <hip/hip_fp16.h>
#include <math.h>

// Problem constants (from reference)
#define RESV 128
#define V3 (RESV*RESV*RESV)          // 2097152 voxels per channel
#define N_RAYS 1024
#define N_SAMPLES 891                // int(257*sqrt(3)/0.5)+1
#define STEP_T 0.0078125f            // STEPSIZE * VOXEL = 0.5 * (2/128)
#define ACT_SHIFT -4.595119850134589f // log(1/(1-0.01) - 1)

typedef short bf16x8 __attribute__((ext_vector_type(8)));
typedef float f32x4 __attribute__((ext_vector_type(4)));

// fp32 -> bf16 bits, round-to-nearest-even
__device__ __forceinline__ unsigned short f2b(float x) {
    unsigned int u = __float_as_uint(x);
    unsigned int r = (u + 0x7FFFu + ((u >> 16) & 1u)) >> 16;
    return (unsigned short)r;
}

// accumulate two bf16 channels packed in one uint into fp32 accumulators
__device__ __forceinline__ void acc2(float w, unsigned int u, float& lo, float& hi) {
    lo = fmaf(w, __uint_as_float(u << 16), lo);
    hi = fmaf(w, __uint_as_float(u & 0xffff0000u), hi);
}

// ---------------------------------------------------------------------------
// Kernel A0: pre-pack MLP weights into MFMA B-fragment-linear order (bf16).
// Fragment (l, ks, nb) = 64 lanes x 8 bf16 (16 B/lane, lane-consecutive ->
// one coalesced global_load_dwordx4 per lane in raymarch). 26 frags = 26 KB,
// L1/L2-hot across all raymarch blocks. Layers 0..2: n = nb*16 + (lane&15),
// k = ks*32 + (lane>>4)*8 + j. Head (frags 24,25): n = lane&15 (<3).
// ---------------------------------------------------------------------------
__global__ __launch_bounds__(256)
void wprep_kernel(const float* __restrict__ w0, const float* __restrict__ w1,
                  const float* __restrict__ w2, const float* __restrict__ w3,
                  unsigned short* __restrict__ wfr) {
    const int t = threadIdx.x;
    for (int i = t; i < 26 * 64 * 8; i += 256) {
        const int j = i & 7;
        const int lane = (i >> 3) & 63;
        const int frag = i >> 9;
        const int r16 = lane & 15, q = lane >> 4;
        float v;
        if (frag < 24) {
            const int l = frag >> 3, ks = (frag >> 2) & 1, nb = frag & 3;
            const int n = nb * 16 + r16;
            const int k = ks * 32 + q * 8 + j;
            const float* W = (l == 0) ? w0 : (l == 1) ? w1 : w2;
            v = (l == 0 && k >= 54) ? 0.f : W[k * 64 + n];
        } else {
            const int ks = frag - 24;
            const int k = ks * 32 + q * 8 + j;
            v = (r16 < 3) ? w3[k * 3 + r16] : 0.f;
        }
        wfr[i] = f2b(v);
    }
}

// ---------------------------------------------------------------------------
// Kernel A1: 5x5x5 conv over density channel -> normalized normals (float4).
// LDS-tiled: block = (1 x) x (8 y) x (128 z); halo'd rows, conflict-free
// b128 reads.
// ---------------------------------------------------------------------------
#define ROWS 60           // 5 x-planes * 12 y-rows
#define ZSTR 136          // z stride in floats

__global__ __launch_bounds__(256)
void normals_conv_kernel(const float* __restrict__ grid,
                         const float* __restrict__ sobel,
                         float4* __restrict__ nrm4) {
    __shared__ float sk[375];
    __shared__ __align__(16) float tile[ROWS * ZSTR];   // 32,640 B

    const int t = threadIdx.x;
    const int bx = blockIdx.x;
    const int ix = bx >> 4;            // 0..127
    const int iy0 = (bx & 15) * 8;     // y tile base

    for (int i = t; i < 375; i += 256) sk[i] = sobel[i];

    {
        const int lane32 = t & 31;
        for (int r = t >> 5; r < ROWS; r += 8) {
            const int xl = r / 12, yl = r % 12;
            const int gx = ix + xl - 2;
            const int gy = iy0 + yl - 2;
            float4 v = make_float4(0.f, 0.f, 0.f, 0.f);
            if ((unsigned)gx < 128u && (unsigned)gy < 128u)
                v = *(const float4*)&grid[(size_t)(gx * 128 + gy) * 128 + lane32 * 4];
            *(float4*)&tile[r * ZSTR + 4 + lane32 * 4] = v;
        }
        if (t < ROWS) {
            float* row = tile + t * ZSTR;
            row[0] = 0.f; row[1] = 0.f; row[2] = 0.f; row[3] = 0.f;
            row[132] = 0.f; row[133] = 0.f; row[134] = 0.f; row[135] = 0.f;
        }
    }
    __syncthreads();

    const int iz4 = (t & 31) * 4;
    const int iyl = t >> 5;

    float c0[4] = {0.f, 0.f, 0.f, 0.f};
    float c1[4] = {0.f, 0.f, 0.f, 0.f};
    float c2[4] = {0.f, 0.f, 0.f, 0.f};

    #pragma unroll
    for (int da = 0; da < 5; ++da) {
        #pragma unroll
        for (int db = 0; db < 5; ++db) {
            const float* row = tile + (da * 12 + iyl + db + 2) * ZSTR;
            const float* k0  = sk + (da * 5 + db) * 5;
            float gbuf[12];
            *(float4*)&gbuf[0] = *(const float4*)&row[iz4];
            *(float4*)&gbuf[4] = *(const float4*)&row[iz4 + 4];
            *(float4*)&gbuf[8] = *(const float4*)&row[iz4 + 8];
            #pragma unroll
            for (int zz = 0; zz < 4; ++zz) {
                #pragma unroll
                for (int dc = 0; dc < 5; ++dc) {
                    const float gv = gbuf[2 + zz + dc];
                    c0[zz] = fmaf(gv, k0[dc],       c0[zz]);
                    c1[zz] = fmaf(gv, k0[125 + dc], c1[zz]);
                    c2[zz] = fmaf(gv, k0[250 + dc], c2[zz]);
                }
            }
        }
    }
    const int vbase = (ix * 128 + iy0 + iyl) * 128 + iz4;
    #pragma unroll
    for (int zz = 0; zz < 4; ++zz) {
        float l   = sqrtf(c0[zz]*c0[zz] + c1[zz]*c1[zz] + c2[zz]*c2[zz]);
        float inv = -1.0f / fmaxf(l, 1e-12f);
        nrm4[vbase + zz] = make_float4(c0[zz]*inv, c1[zz]*inv, c2[zz]*inv, 0.f);
    }
}

// ---------------------------------------------------------------------------
// Kernel A2: streaming repack, channel-planar fp32 -> voxel-interleaved bf16.
// ---------------------------------------------------------------------------
__global__ __launch_bounds__(256)
void repack_kernel(const float* __restrict__ grid,
                   unsigned short* __restrict__ latp) {
    const int i = blockIdx.x * 256 + threadIdx.x;   // 0 .. V3/4-1
    const int v0 = i * 4;
    unsigned int r[4][8];
    #pragma unroll
    for (int c = 0; c < 16; c += 2) {
        const float4 a = *(const float4*)&grid[(size_t)c * V3 + v0];
        const float4 b = *(const float4*)&grid[(size_t)(c + 1) * V3 + v0];
        const float* pa = &a.x; const float* pb = &b.x;
        #pragma unroll
        for (int z = 0; z < 4; ++z)
            r[z][c >> 1] = (unsigned int)f2b(pa[z]) | ((unsigned int)f2b(pb[z]) << 16);
    }
    uint4* d = (uint4*)&latp[(size_t)v0 * 16];
    #pragma unroll
    for (int z = 0; z < 4; ++z) {
        d[z * 2 + 0] = make_uint4(r[z][0], r[z][1], r[z][2], r[z][3]);
        d[z * 2 + 1] = make_uint4(r[z][4], r[z][5], r[z][6], r[z][7]);
    }
}

// ---------------------------------------------------------------------------
// One MFMA MLP layer. A-frags from per-wave LDS tile; B-frags as coalesced
// 16 B global loads from the fragment-linear weight pack (L1/L2-hot).
// ---------------------------------------------------------------------------
__device__ __forceinline__ void mfma_layer(unsigned short* __restrict__ actw,
                                           const unsigned short* __restrict__ wfr,
                                           int l, const float* __restrict__ Bv,
                                           int lane, int r16, int q4, int q8) {
    f32x4 acc[4][4];
    #pragma unroll
    for (int nb = 0; nb < 4; ++nb) {
        const float bv = Bv[nb * 16 + r16];
        #pragma unroll
        for (int mb = 0; mb < 4; ++mb) {
            acc[mb][nb][0] = bv; acc[mb][nb][1] = bv;
            acc[mb][nb][2] = bv; acc[mb][nb][3] = bv;
        }
    }
    #pragma unroll
    for (int ks = 0; ks < 2; ++ks) {
        bf16x8 Af[4], Bf[4];
        #pragma unroll
        for (int mb = 0; mb < 4; ++mb)
            Af[mb] = *(const bf16x8*)&actw[(mb * 16 + r16) * 72 + ks * 32 + q8];
        #pragma unroll
        for (int nb = 0; nb < 4; ++nb)
            Bf[nb] = *(const bf16x8*)&wfr[(size_t)((((l * 2 + ks) * 4) + nb) * 64 + lane) * 8];
        #pragma unroll
        for (int mb = 0; mb < 4; ++mb) {
            #pragma unroll
            for (int nb = 0; nb < 4; ++nb)
                acc[mb][nb] = __builtin_amdgcn_mfma_f32_16x16x32_bf16(
                    Af[mb], Bf[nb], acc[mb][nb], 0, 0, 0);
        }
    }
    #pragma unroll
    for (int mb = 0; mb < 4; ++mb) {
        #pragma unroll
        for (int nb = 0; nb < 4; ++nb) {
            #pragma unroll
            for (int r = 0; r < 4; ++r) {
                const int row = mb * 16 + q4 + r;
                actw[row * 72 + nb * 16 + r16] = f2b(fmaxf(acc[mb][nb][r], 0.f));
            }
        }
    }
}

// ---------------------------------------------------------------------------
// Kernel B: one block per ray, 4 waves. LDS ~51 KB -> 3 blocks/CU (was 81 KB
// -> 2). __launch_bounds__(256,3) caps VGPR at ~170 (natural ~140, no spill).
// ---------------------------------------------------------------------------
template <bool PL>
__global__ __launch_bounds__(256, 3)
void raymarch_kernel(const float* __restrict__ ro, const float* __restrict__ rd,
                     const float* __restrict__ vd, const float* __restrict__ grid,
                     const float4* __restrict__ nrm4,
                     const unsigned short* __restrict__ latp,
                     const unsigned short* __restrict__ wfr,
                     const float* __restrict__ b0, const float* __restrict__ b1,
                     const float* __restrict__ b2, const float* __restrict__ b3,
                     float* __restrict__ out) {
    __shared__ __align__(16) unsigned short act[4 * 64 * 72]; // 36,864 B
    __shared__ float sb0f[64], sb1f[64], sb2f[64], sb3f[16];
    __shared__ __half salpha[1024];
    __shared__ __half scr[1024], scg[1024], scb[1024];
    __shared__ float lgl[1024];
    __shared__ float aux[256];
    __shared__ float red[12];

    const int t = threadIdx.x;
    const int ray = blockIdx.x;
    const int lane = t & 63;
    const int wave = t >> 6;
    const int r16 = lane & 15;
    const int q4 = (lane >> 4) * 4;
    const int q8 = (lane >> 4) * 8;
    unsigned short* const actw = act + wave * 64 * 72;

    if (t < 64) { sb0f[t] = b0[t]; sb1f[t] = b1[t]; sb2f[t] = b2[t]; }
    if (t < 16) sb3f[t] = (t < 3) ? b3[t] : 0.f;
    __syncthreads();

    const float ox = ro[ray * 3 + 0], oy = ro[ray * 3 + 1], oz = ro[ray * 3 + 2];
    const float dx = rd[ray * 3 + 0], dyv = rd[ray * 3 + 1], dzv = rd[ray * 3 + 2];
    const float vx = vd[ray * 3 + 0], vy = vd[ray * 3 + 1], vz = vd[ray * 3 + 2];

    const float ex = (dx  == 0.f) ? 1e-6f : dx;
    const float ey = (dyv == 0.f) ? 1e-6f : dyv;
    const float ez = (dzv == 0.f) ? 1e-6f : dzv;
    const float rax = (1.f - ox) / ex, rbx = (-1.f - ox) / ex;
    const float ray_ = (1.f - oy) / ey, rby = (-1.f - oy) / ey;
    const float raz = (1.f - oz) / ez, rbz = (-1.f - oz) / ez;
    float tmin = fmaxf(fmaxf(fminf(rax, rbx), fminf(ray_, rby)), fminf(raz, rbz));
    float tmax = fminf(fminf(fmaxf(rax, rbx), fmaxf(ray_, rby)), fmaxf(raz, rbz));
    tmin = fminf(fmaxf(tmin, 0.2f), 3.0f);
    tmax = fminf(fmaxf(tmax, 0.2f), 3.0f);
    const bool mask_ray = (tmax <= tmin);
    const float invn = 1.0f / sqrtf(dx * dx + dyv * dyv + dzv * dzv);

    #pragma unroll 1
    for (int j = 0; j < 4; ++j) {
        const int s = j * 256 + t;
        float alpha_s = 0.f;
        bool active = (s < N_SAMPLES) && !mask_ray;
        float px = 0.f, py = 0.f, pz = 0.f;
        if (active) {
            const float ti = tmin + STEP_T * (float)s * invn;
            px = fmaf(dx, ti, ox);
            py = fmaf(dyv, ti, oy);
            pz = fmaf(dzv, ti, oz);
            active = !(px < -1.f || px > 1.f || py < -1.f || py > 1.f ||
                       pz < -1.f || pz > 1.f);
        }
        const unsigned long long wmask = __ballot(active);
        if (wmask == 0ull) {
            salpha[s] = __float2half(0.f);
            lgl[s] = 0.f;
            scr[s] = __float2half(0.f); scg[s] = __float2half(0.f);
            scb[s] = __float2half(0.f);
            continue;
        }

        float feat[54];
        #pragma unroll
        for (int i = 0; i < 54; ++i) feat[i] = 0.f;

        if (active) {
            const float ga = (px + 1.f) * 63.5f;
            const float gb = (py + 1.f) * 63.5f;
            const float gc = (pz + 1.f) * 63.5f;
            const float fla = floorf(ga), flb = floorf(gb), flc = floorf(gc);
            const float fa = ga - fla, fb = gb - flb, fc = gc - flc;
            int ia0 = min(max((int)fla, 0), 127);
            int ib0 = min(max((int)flb, 0), 127);
            int ic0 = min(max((int)flc, 0), 127);
            int ia1 = min(ia0 + 1, 127);
            int ib1 = min(ib0 + 1, 127);
            int ic1 = min(ic0 + 1, 127);
            const int base00 = (ia0 * 128 + ib0) * 128;
            const int base01 = (ia0 * 128 + ib1) * 128;
            const int base10 = (ia1 * 128 + ib0) * 128;
            const int base11 = (ia1 * 128 + ib1) * 128;
            int idxs[8] = { base00 + ic0, base00 + ic1, base01 + ic0, base01 + ic1,
                            base10 + ic0, base10 + ic1, base11 + ic0, base11 + ic1 };
            const float wa0 = 1.f - fa, wb0 = 1.f - fb, wc0 = 1.f - fc;
            float w8[8] = { wa0*wb0*wc0, wa0*wb0*fc, wa0*fb*wc0, wa0*fb*fc,
                            fa*wb0*wc0,  fa*wb0*fc,  fa*fb*wc0,  fa*fb*fc };

            float lat[16];
            #pragma unroll
            for (int c = 0; c < 16; ++c) lat[c] = 0.f;
            if constexpr (PL) {
                #pragma unroll
                for (int k = 0; k < 8; ++k) {
                    const uint4* rec = (const uint4*)&latp[(size_t)idxs[k] * 16];
                    const uint4 u0 = rec[0];
                    const uint4 u1 = rec[1];
                    const float w = w8[k];
                    acc2(w, u0.x, lat[0],  lat[1]);
                    acc2(w, u0.y, lat[2],  lat[3]);
                    acc2(w, u0.z, lat[4],  lat[5]);
                    acc2(w, u0.w, lat[6],  lat[7]);
                    acc2(w, u1.x, lat[8],  lat[9]);
                    acc2(w, u1.y, lat[10], lat[11]);
                    acc2(w, u1.z, lat[12], lat[13]);
                    acc2(w, u1.w, lat[14], lat[15]);
                }
            } else {
                #pragma unroll
                for (int c = 0; c < 16; ++c) {
                    const float* gcp = grid + (size_t)c * V3;
                    float acc = 0.f;
                    #pragma unroll
                    for (int k = 0; k < 8; ++k) acc = fmaf(w8[k], gcp[idxs[k]], acc);
                    lat[c] = acc;
                }
            }
            const float lat0 = lat[0];
            #pragma unroll
            for (int c = 0; c < 15; ++c) feat[c] = lat[c + 1];

            float n0 = 0.f, n1 = 0.f, n2 = 0.f;
            #pragma unroll
            for (int k = 0; k < 8; ++k) {
                const float4 nv = nrm4[idxs[k]];
                n0 = fmaf(w8[k], nv.x, n0);
                n1 = fmaf(w8[k], nv.y, n1);
                n2 = fmaf(w8[k], nv.z, n2);
            }
            const float nl = sqrtf(n0*n0 + n1*n1 + n2*n2);
            const float ninv = -1.0f / fmaxf(nl, 1e-12f);
            n0 *= ninv; n1 *= ninv; n2 *= ninv;
            const float dotv = -(vx * n0 + vy * n1 + vz * n2);
            const float rx = fmaf(2.f * dotv, n0, vx);
            const float ry = fmaf(2.f * dotv, n1, vy);
            const float rz = fmaf(2.f * dotv, n2, vz);

            const float d0 = lat0 + ACT_SHIFT;
            const float sp = (d0 > 20.f) ? d0 : __logf(1.f + __expf(d0));
            alpha_s = 1.f - __expf(-sp * 0.5f);

            feat[15] = rx; feat[16] = ry; feat[17] = rz;
            float fr = 1.f;
            #pragma unroll
            for (int k = 0; k < 6; ++k) {
                feat[18 + k*3 + 0] = __sinf(rx * fr);
                feat[18 + k*3 + 1] = __sinf(ry * fr);
                feat[18 + k*3 + 2] = __sinf(rz * fr);
                feat[36 + k*3 + 0] = __cosf(rx * fr);
                feat[36 + k*3 + 1] = __cosf(ry * fr);
                feat[36 + k*3 + 2] = __cosf(rz * fr);
                fr *= 2.f;
            }
        }
        salpha[s] = __float2half(alpha_s);
        lgl[s] = __logf(fmaxf(1.f - alpha_s, 1e-10f));

        unsigned int* arow = (unsigned int*)&act[(size_t)t * 72];
        #pragma unroll
        for (int p = 0; p < 27; ++p)
            arow[p] = (unsigned int)f2b(feat[2*p]) |
                      ((unsigned int)f2b(feat[2*p + 1]) << 16);
        #pragma unroll
        for (int p = 27; p < 32; ++p) arow[p] = 0u;

        mfma_layer(actw, wfr, 0, sb0f, lane, r16, q4, q8);
        mfma_layer(actw, wfr, 1, sb1f, lane, r16, q4, q8);
        mfma_layer(actw, wfr, 2, sb2f, lane, r16, q4, q8);

        {
            f32x4 acch[4];
            const float bv = sb3f[r16];
            #pragma unroll
            for (int mb = 0; mb < 4; ++mb) {
                acch[mb][0] = bv; acch[mb][1] = bv;
                acch[mb][2] = bv; acch[mb][3] = bv;
            }
            #pragma unroll
            for (int ks = 0; ks < 2; ++ks) {
                const bf16x8 Bh = *(const bf16x8*)&wfr[(size_t)((24 + ks) * 64 + lane) * 8];
                #pragma unroll
                for (int mb = 0; mb < 4; ++mb) {
                    const bf16x8 Af = *(const bf16x8*)&actw[(mb * 16 + r16) * 72 + ks * 32 + q8];
                    acch[mb] = __builtin_amdgcn_mfma_f32_16x16x32_bf16(Af, Bh, acch[mb], 0, 0, 0);
                }
            }
            if (r16 < 3) {
                __half* dst = (r16 == 0) ? scr : (r16 == 1) ? scg : scb;
                const int jb = j * 256 + wave * 64;
                #pragma unroll
                for (int mb = 0; mb < 4; ++mb) {
                    #pragma unroll
                    for (int r = 0; r < 4; ++r) {
                        const int samp = mb * 16 + q4 + r;
                        dst[jb + samp] = __float2half(1.f / (1.f + __expf(-acch[mb][r])));
                    }
                }
            }
        }
    }
    __syncthreads();

    {
        float c0 = lgl[4*t + 0];
        float c1 = c0 + lgl[4*t + 1];
        float c2 = c1 + lgl[4*t + 2];
        float c3 = c2 + lgl[4*t + 3];
        lgl[4*t + 0] = c0; lgl[4*t + 1] = c1;
        lgl[4*t + 2] = c2; lgl[4*t + 3] = c3;
        aux[t] = c3;
    }
    __syncthreads();
    for (int off = 1; off < 256; off <<= 1) {
        const float v = (t >= off) ? aux[t - off] : 0.f;
        __syncthreads();
        aux[t] += v;
        __syncthreads();
    }
    const float total = aux[255];

    float r0 = 0.f, r1 = 0.f, r2 = 0.f;
    #pragma unroll
    for (int j = 0; j < 4; ++j) {
        const int s = j * 256 + t;
        const float a = __half2float(salpha[s]);
        if (s < N_SAMPLES && a > 0.f) {
            float G;
            if (s == 0) G = 0.f;
            else {
                const int m = s - 1;
                G = lgl[m] + (((m >> 2) > 0) ? aux[(m >> 2) - 1] : 0.f);
            }
            const float T = __expf(G);
            const float w = a * T;
            r0 = fmaf(w, __half2float(scr[s]), r0);
            r1 = fmaf(w, __half2float(scg[s]), r1);
            r2 = fmaf(w, __half2float(scb[s]), r2);
        }
    }
    #pragma unroll
    for (int off = 32; off > 0; off >>= 1) {
        r0 += __shfl_down(r0, off, 64);
        r1 += __shfl_down(r1, off, 64);
        r2 += __shfl_down(r2, off, 64);
    }
    if ((t & 63) == 0) {
        red[wave * 3 + 0] = r0; red[wave * 3 + 1] = r1; red[wave * 3 + 2] = r2;
    }
    __syncthreads();
    if (t == 0) {
        const float Tf = __expf(total);
        out[ray * 3 + 0] = red[0] + red[3] + red[6] + red[9]  + Tf;
        out[ray * 3 + 1] = red[1] + red[4] + red[7] + red[10] + Tf;
        out[ray * 3 + 2] = red[2] + red[5] + red[8] + red[11] + Tf;
    }
}

extern "C" void kernel_launch(void* const* d_in, const int* in_sizes, int n_in,
                              void* d_out, int out_size, void* d_ws, size_t ws_size,
                              hipStream_t stream) {
    (void)in_sizes; (void)n_in; (void)out_size;
    const float* ro    = (const float*)d_in[0];
    const float* rd    = (const float*)d_in[1];
    const float* vd    = (const float*)d_in[2];
    const float* grid  = (const float*)d_in[3];
    const float* sobel = (const float*)d_in[4];
    const float* w0 = (const float*)d_in[5];
    const float* b0 = (const float*)d_in[6];
    const float* w1 = (const float*)d_in[7];
    const float* b1 = (const float*)d_in[8];
    const float* w2 = (const float*)d_in[9];
    const float* b2 = (const float*)d_in[10];
    const float* w3 = (const float*)d_in[11];
    const float* b3 = (const float*)d_in[12];

    const size_t NRM_BYTES = (size_t)V3 * 16;            // 32 MB
    const size_t LAT_BYTES = (size_t)V3 * 32;            // 64 MB
    const size_t WFR_BYTES = 26 * 64 * 8 * 2;            // 26,624 B
    float4* nrm4 = (float4*)d_ws;
    const bool packed = (ws_size >= NRM_BYTES + LAT_BYTES + WFR_BYTES);
    unsigned short* latp = (unsigned short*)((char*)d_ws + NRM_BYTES);
    unsigned short* wfr  = packed
        ? (unsigned short*)((char*)d_ws + NRM_BYTES + LAT_BYTES)
        : (unsigned short*)((char*)d_ws + NRM_BYTES);

    wprep_kernel<<<1, 256, 0, stream>>>(w0, w1, w2, w3, wfr);
    normals_conv_kernel<<<128 * 16, 256, 0, stream>>>(grid, sobel, nrm4);
    if (packed) {
        repack_kernel<<<V3 / 4 / 256, 256, 0, stream>>>(grid, latp);
        raymarch_kernel<true><<<N_RAYS, 256, 0, stream>>>(ro, rd, vd, grid, nrm4, latp, wfr,
                                                          b0, b1, b2, b3, (float*)d_out);
    } else {
        raymarch_kernel<false><<<N_RAYS, 256, 0, stream>>>(ro, rd, vd, grid, nrm4, latp, wfr,
                                                           b0, b1, b2, b3, (float*)d_out);
    }
}

// Round 10
// 305.553 us; speedup vs baseline: 1.1517x; 1.1517x over previous
//
#include <hip/hip_runtime.h>
#include <hip/hip_bf16.h>
#include <hip/hip_fp16.h>
#include <math.h>

// Problem constants (from reference)
#define RESV 128
#define V3 (RESV*RESV*RESV)          // 2097152 voxels per channel
#define N_RAYS 1024
#define N_SAMPLES 891                // int(257*sqrt(3)/0.5)+1
#define STEP_T 0.0078125f            // STEPSIZE * VOXEL = 0.5 * (2/128)
#define ACT_SHIFT -4.595119850134589f // log(1/(1-0.01) - 1)

typedef short bf16x8 __attribute__((ext_vector_type(8)));
typedef float f32x4 __attribute__((ext_vector_type(4)));

// fp32 -> bf16 bits, round-to-nearest-even
__device__ __forceinline__ unsigned short f2b(float x) {
    unsigned int u = __float_as_uint(x);
    unsigned int r = (u + 0x7FFFu + ((u >> 16) & 1u)) >> 16;
    return (unsigned short)r;
}

// accumulate two bf16 channels packed in one uint into fp32 accumulators
__device__ __forceinline__ void acc2(float w, unsigned int u, float& lo, float& hi) {
    lo = fmaf(w, __uint_as_float(u << 16), lo);
    hi = fmaf(w, __uint_as_float(u & 0xffff0000u), hi);
}

// ---------------------------------------------------------------------------
// Kernel A (fused prep): per block (1 x) x (8 y) x (128 z):
//   1. LDS-tiled 5x5x5 conv -> normalized normals (float4 records)   [VALU]
//   2. repack the same 4 voxels/thread: 16 fp32 planes -> 32 B bf16  [VMEM]
//   3. block 0 only: pre-pack MLP weights into B-fragment order      [tiny]
// The stencil is compute-bound and the repack pure streaming: they overlap
// pipes (round-6's slow fusion had a latency-bound conv; round-8 fixed that).
// ---------------------------------------------------------------------------
#define ROWS 60           // 5 x-planes * 12 y-rows
#define ZSTR 136          // z stride in floats

template <bool PL>
__global__ __launch_bounds__(256)
void prep_kernel(const float* __restrict__ grid,
                 const float* __restrict__ sobel,
                 float4* __restrict__ nrm4,
                 unsigned short* __restrict__ latp,
                 const float* __restrict__ w0, const float* __restrict__ w1,
                 const float* __restrict__ w2, const float* __restrict__ w3,
                 unsigned short* __restrict__ wfr) {
    __shared__ float sk[375];
    __shared__ __align__(16) float tile[ROWS * ZSTR];   // 32,640 B

    const int t = threadIdx.x;
    const int bx = blockIdx.x;
    const int ix = bx >> 4;            // 0..127
    const int iy0 = (bx & 15) * 8;     // y tile base

    // --- weight pre-pack (one block; overlaps with everything else) ---
    if (bx == 0) {
        for (int i = t; i < 26 * 64 * 8; i += 256) {
            const int j = i & 7;
            const int lane = (i >> 3) & 63;
            const int frag = i >> 9;
            const int r16 = lane & 15, q = lane >> 4;
            float v;
            if (frag < 24) {
                const int l = frag >> 3, ks = (frag >> 2) & 1, nb = frag & 3;
                const int n = nb * 16 + r16;
                const int k = ks * 32 + q * 8 + j;
                const float* W = (l == 0) ? w0 : (l == 1) ? w1 : w2;
                v = (l == 0 && k >= 54) ? 0.f : W[k * 64 + n];
            } else {
                const int ks = frag - 24;
                const int k = ks * 32 + q * 8 + j;
                v = (r16 < 3) ? w3[k * 3 + r16] : 0.f;
            }
            wfr[i] = f2b(v);
        }
    }

    for (int i = t; i < 375; i += 256) sk[i] = sobel[i];

    // --- stage halo'd density tile ---
    {
        const int lane32 = t & 31;
        for (int r = t >> 5; r < ROWS; r += 8) {
            const int xl = r / 12, yl = r % 12;
            const int gx = ix + xl - 2;
            const int gy = iy0 + yl - 2;
            float4 v = make_float4(0.f, 0.f, 0.f, 0.f);
            if ((unsigned)gx < 128u && (unsigned)gy < 128u)
                v = *(const float4*)&grid[(size_t)(gx * 128 + gy) * 128 + lane32 * 4];
            *(float4*)&tile[r * ZSTR + 4 + lane32 * 4] = v;
        }
        if (t < ROWS) {
            float* row = tile + t * ZSTR;
            row[0] = 0.f; row[1] = 0.f; row[2] = 0.f; row[3] = 0.f;
            row[132] = 0.f; row[133] = 0.f; row[134] = 0.f; row[135] = 0.f;
        }
    }
    __syncthreads();

    const int iz4 = (t & 31) * 4;
    const int iyl = t >> 5;
    const int vbase = (ix * 128 + iy0 + iyl) * 128 + iz4;

    // --- conv from LDS (conflict-free b128 reads) ---
    float c0[4] = {0.f, 0.f, 0.f, 0.f};
    float c1[4] = {0.f, 0.f, 0.f, 0.f};
    float c2[4] = {0.f, 0.f, 0.f, 0.f};

    #pragma unroll
    for (int da = 0; da < 5; ++da) {
        #pragma unroll
        for (int db = 0; db < 5; ++db) {
            const float* row = tile + (da * 12 + iyl + db + 2) * ZSTR;
            const float* k0  = sk + (da * 5 + db) * 5;
            float gbuf[12];
            *(float4*)&gbuf[0] = *(const float4*)&row[iz4];
            *(float4*)&gbuf[4] = *(const float4*)&row[iz4 + 4];
            *(float4*)&gbuf[8] = *(const float4*)&row[iz4 + 8];
            #pragma unroll
            for (int zz = 0; zz < 4; ++zz) {
                #pragma unroll
                for (int dc = 0; dc < 5; ++dc) {
                    const float gv = gbuf[2 + zz + dc];
                    c0[zz] = fmaf(gv, k0[dc],       c0[zz]);
                    c1[zz] = fmaf(gv, k0[125 + dc], c1[zz]);
                    c2[zz] = fmaf(gv, k0[250 + dc], c2[zz]);
                }
            }
        }
    }
    #pragma unroll
    for (int zz = 0; zz < 4; ++zz) {
        float l   = sqrtf(c0[zz]*c0[zz] + c1[zz]*c1[zz] + c2[zz]*c2[zz]);
        float inv = -1.0f / fmaxf(l, 1e-12f);
        nrm4[vbase + zz] = make_float4(c0[zz]*inv, c1[zz]*inv, c2[zz]*inv, 0.f);
    }

    // --- repack the same 4 voxels (pure streaming, coalesced) ---
    if constexpr (PL) {
        unsigned int r[4][8];
        #pragma unroll
        for (int c = 0; c < 16; c += 2) {
            const float4 a = *(const float4*)&grid[(size_t)c * V3 + vbase];
            const float4 b = *(const float4*)&grid[(size_t)(c + 1) * V3 + vbase];
            const float* pa = &a.x; const float* pb = &b.x;
            #pragma unroll
            for (int z = 0; z < 4; ++z)
                r[z][c >> 1] = (unsigned int)f2b(pa[z]) | ((unsigned int)f2b(pb[z]) << 16);
        }
        uint4* d = (uint4*)&latp[(size_t)vbase * 16];
        #pragma unroll
        for (int z = 0; z < 4; ++z) {
            d[z * 2 + 0] = make_uint4(r[z][0], r[z][1], r[z][2], r[z][3]);
            d[z * 2 + 1] = make_uint4(r[z][4], r[z][5], r[z][6], r[z][7]);
        }
    }
}

// ---------------------------------------------------------------------------
// One MFMA MLP layer. A-frags from per-wave LDS tile; B-frags as coalesced
// 16 B global loads from the fragment-linear weight pack (L1/L2-hot).
// ---------------------------------------------------------------------------
__device__ __forceinline__ void mfma_layer(unsigned short* __restrict__ actw,
                                           const unsigned short* __restrict__ wfr,
                                           int l, const float* __restrict__ Bv,
                                           int lane, int r16, int q4, int q8) {
    f32x4 acc[4][4];
    #pragma unroll
    for (int nb = 0; nb < 4; ++nb) {
        const float bv = Bv[nb * 16 + r16];
        #pragma unroll
        for (int mb = 0; mb < 4; ++mb) {
            acc[mb][nb][0] = bv; acc[mb][nb][1] = bv;
            acc[mb][nb][2] = bv; acc[mb][nb][3] = bv;
        }
    }
    #pragma unroll
    for (int ks = 0; ks < 2; ++ks) {
        bf16x8 Af[4], Bf[4];
        #pragma unroll
        for (int mb = 0; mb < 4; ++mb)
            Af[mb] = *(const bf16x8*)&actw[(mb * 16 + r16) * 72 + ks * 32 + q8];
        #pragma unroll
        for (int nb = 0; nb < 4; ++nb)
            Bf[nb] = *(const bf16x8*)&wfr[(size_t)((((l * 2 + ks) * 4) + nb) * 64 + lane) * 8];
        #pragma unroll
        for (int mb = 0; mb < 4; ++mb) {
            #pragma unroll
            for (int nb = 0; nb < 4; ++nb)
                acc[mb][nb] = __builtin_amdgcn_mfma_f32_16x16x32_bf16(
                    Af[mb], Bf[nb], acc[mb][nb], 0, 0, 0);
        }
    }
    #pragma unroll
    for (int mb = 0; mb < 4; ++mb) {
        #pragma unroll
        for (int nb = 0; nb < 4; ++nb) {
            #pragma unroll
            for (int r = 0; r < 4; ++r) {
                const int row = mb * 16 + q4 + r;
                actw[row * 72 + nb * 16 + r16] = f2b(fmaxf(acc[mb][nb][r], 0.f));
            }
        }
    }
}

// ---------------------------------------------------------------------------
// Kernel B: one block per ray, 4 waves. LDS ~51 KB -> 3 blocks/CU.
// ---------------------------------------------------------------------------
template <bool PL>
__global__ __launch_bounds__(256, 3)
void raymarch_kernel(const float* __restrict__ ro, const float* __restrict__ rd,
                     const float* __restrict__ vd, const float* __restrict__ grid,
                     const float4* __restrict__ nrm4,
                     const unsigned short* __restrict__ latp,
                     const unsigned short* __restrict__ wfr,
                     const float* __restrict__ b0, const float* __restrict__ b1,
                     const float* __restrict__ b2, const float* __restrict__ b3,
                     float* __restrict__ out) {
    __shared__ __align__(16) unsigned short act[4 * 64 * 72]; // 36,864 B
    __shared__ float sb0f[64], sb1f[64], sb2f[64], sb3f[16];
    __shared__ __half salpha[1024];
    __shared__ __half scr[1024], scg[1024], scb[1024];
    __shared__ float lgl[1024];
    __shared__ float aux[256];
    __shared__ float red[12];

    const int t = threadIdx.x;
    const int ray = blockIdx.x;
    const int lane = t & 63;
    const int wave = t >> 6;
    const int r16 = lane & 15;
    const int q4 = (lane >> 4) * 4;
    const int q8 = (lane >> 4) * 8;
    unsigned short* const actw = act + wave * 64 * 72;

    if (t < 64) { sb0f[t] = b0[t]; sb1f[t] = b1[t]; sb2f[t] = b2[t]; }
    if (t < 16) sb3f[t] = (t < 3) ? b3[t] : 0.f;
    __syncthreads();

    const float ox = ro[ray * 3 + 0], oy = ro[ray * 3 + 1], oz = ro[ray * 3 + 2];
    const float dx = rd[ray * 3 + 0], dyv = rd[ray * 3 + 1], dzv = rd[ray * 3 + 2];
    const float vx = vd[ray * 3 + 0], vy = vd[ray * 3 + 1], vz = vd[ray * 3 + 2];

    const float ex = (dx  == 0.f) ? 1e-6f : dx;
    const float ey = (dyv == 0.f) ? 1e-6f : dyv;
    const float ez = (dzv == 0.f) ? 1e-6f : dzv;
    const float rax = (1.f - ox) / ex, rbx = (-1.f - ox) / ex;
    const float ray_ = (1.f - oy) / ey, rby = (-1.f - oy) / ey;
    const float raz = (1.f - oz) / ez, rbz = (-1.f - oz) / ez;
    float tmin = fmaxf(fmaxf(fminf(rax, rbx), fminf(ray_, rby)), fminf(raz, rbz));
    float tmax = fminf(fminf(fmaxf(rax, rbx), fmaxf(ray_, rby)), fmaxf(raz, rbz));
    tmin = fminf(fmaxf(tmin, 0.2f), 3.0f);
    tmax = fminf(fmaxf(tmax, 0.2f), 3.0f);
    const bool mask_ray = (tmax <= tmin);
    const float invn = 1.0f / sqrtf(dx * dx + dyv * dyv + dzv * dzv);

    #pragma unroll 1
    for (int j = 0; j < 4; ++j) {
        const int s = j * 256 + t;
        float alpha_s = 0.f;
        bool active = (s < N_SAMPLES) && !mask_ray;
        float px = 0.f, py = 0.f, pz = 0.f;
        if (active) {
            const float ti = tmin + STEP_T * (float)s * invn;
            px = fmaf(dx, ti, ox);
            py = fmaf(dyv, ti, oy);
            pz = fmaf(dzv, ti, oz);
            active = !(px < -1.f || px > 1.f || py < -1.f || py > 1.f ||
                       pz < -1.f || pz > 1.f);
        }
        const unsigned long long wmask = __ballot(active);
        if (wmask == 0ull) {
            salpha[s] = __float2half(0.f);
            lgl[s] = 0.f;
            scr[s] = __float2half(0.f); scg[s] = __float2half(0.f);
            scb[s] = __float2half(0.f);
            continue;
        }

        float feat[54];
        #pragma unroll
        for (int i = 0; i < 54; ++i) feat[i] = 0.f;

        if (active) {
            const float ga = (px + 1.f) * 63.5f;
            const float gb = (py + 1.f) * 63.5f;
            const float gc = (pz + 1.f) * 63.5f;
            const float fla = floorf(ga), flb = floorf(gb), flc = floorf(gc);
            const float fa = ga - fla, fb = gb - flb, fc = gc - flc;
            int ia0 = min(max((int)fla, 0), 127);
            int ib0 = min(max((int)flb, 0), 127);
            int ic0 = min(max((int)flc, 0), 127);
            int ia1 = min(ia0 + 1, 127);
            int ib1 = min(ib0 + 1, 127);
            int ic1 = min(ic0 + 1, 127);
            const int base00 = (ia0 * 128 + ib0) * 128;
            const int base01 = (ia0 * 128 + ib1) * 128;
            const int base10 = (ia1 * 128 + ib0) * 128;
            const int base11 = (ia1 * 128 + ib1) * 128;
            int idxs[8] = { base00 + ic0, base00 + ic1, base01 + ic0, base01 + ic1,
                            base10 + ic0, base10 + ic1, base11 + ic0, base11 + ic1 };
            const float wa0 = 1.f - fa, wb0 = 1.f - fb, wc0 = 1.f - fc;
            float w8[8] = { wa0*wb0*wc0, wa0*wb0*fc, wa0*fb*wc0, wa0*fb*fc,
                            fa*wb0*wc0,  fa*wb0*fc,  fa*fb*wc0,  fa*fb*fc };

            float lat[16];
            #pragma unroll
            for (int c = 0; c < 16; ++c) lat[c] = 0.f;
            if constexpr (PL) {
                #pragma unroll
                for (int k = 0; k < 8; ++k) {
                    const uint4* rec = (const uint4*)&latp[(size_t)idxs[k] * 16];
                    const uint4 u0 = rec[0];
                    const uint4 u1 = rec[1];
                    const float w = w8[k];
                    acc2(w, u0.x, lat[0],  lat[1]);
                    acc2(w, u0.y, lat[2],  lat[3]);
                    acc2(w, u0.z, lat[4],  lat[5]);
                    acc2(w, u0.w, lat[6],  lat[7]);
                    acc2(w, u1.x, lat[8],  lat[9]);
                    acc2(w, u1.y, lat[10], lat[11]);
                    acc2(w, u1.z, lat[12], lat[13]);
                    acc2(w, u1.w, lat[14], lat[15]);
                }
            } else {
                #pragma unroll
                for (int c = 0; c < 16; ++c) {
                    const float* gcp = grid + (size_t)c * V3;
                    float acc = 0.f;
                    #pragma unroll
                    for (int k = 0; k < 8; ++k) acc = fmaf(w8[k], gcp[idxs[k]], acc);
                    lat[c] = acc;
                }
            }
            const float lat0 = lat[0];
            #pragma unroll
            for (int c = 0; c < 15; ++c) feat[c] = lat[c + 1];

            float n0 = 0.f, n1 = 0.f, n2 = 0.f;
            #pragma unroll
            for (int k = 0; k < 8; ++k) {
                const float4 nv = nrm4[idxs[k]];
                n0 = fmaf(w8[k], nv.x, n0);
                n1 = fmaf(w8[k], nv.y, n1);
                n2 = fmaf(w8[k], nv.z, n2);
            }
            const float nl = sqrtf(n0*n0 + n1*n1 + n2*n2);
            const float ninv = -1.0f / fmaxf(nl, 1e-12f);
            n0 *= ninv; n1 *= ninv; n2 *= ninv;
            const float dotv = -(vx * n0 + vy * n1 + vz * n2);
            const float rx = fmaf(2.f * dotv, n0, vx);
            const float ry = fmaf(2.f * dotv, n1, vy);
            const float rz = fmaf(2.f * dotv, n2, vz);

            const float d0 = lat0 + ACT_SHIFT;
            const float sp = (d0 > 20.f) ? d0 : __logf(1.f + __expf(d0));
            alpha_s = 1.f - __expf(-sp * 0.5f);

            feat[15] = rx; feat[16] = ry; feat[17] = rz;
            float fr = 1.f;
            #pragma unroll
            for (int k = 0; k < 6; ++k) {
                feat[18 + k*3 + 0] = __sinf(rx * fr);
                feat[18 + k*3 + 1] = __sinf(ry * fr);
                feat[18 + k*3 + 2] = __sinf(rz * fr);
                feat[36 + k*3 + 0] = __cosf(rx * fr);
                feat[36 + k*3 + 1] = __cosf(ry * fr);
                feat[36 + k*3 + 2] = __cosf(rz * fr);
                fr *= 2.f;
            }
        }
        salpha[s] = __float2half(alpha_s);
        lgl[s] = __logf(fmaxf(1.f - alpha_s, 1e-10f));

        unsigned int* arow = (unsigned int*)&act[(size_t)t * 72];
        #pragma unroll
        for (int p = 0; p < 27; ++p)
            arow[p] = (unsigned int)f2b(feat[2*p]) |
                      ((unsigned int)f2b(feat[2*p + 1]) << 16);
        #pragma unroll
        for (int p = 27; p < 32; ++p) arow[p] = 0u;

        mfma_layer(actw, wfr, 0, sb0f, lane, r16, q4, q8);
        mfma_layer(actw, wfr, 1, sb1f, lane, r16, q4, q8);
        mfma_layer(actw, wfr, 2, sb2f, lane, r16, q4, q8);

        {
            f32x4 acch[4];
            const float bv = sb3f[r16];
            #pragma unroll
            for (int mb = 0; mb < 4; ++mb) {
                acch[mb][0] = bv; acch[mb][1] = bv;
                acch[mb][2] = bv; acch[mb][3] = bv;
            }
            #pragma unroll
            for (int ks = 0; ks < 2; ++ks) {
                const bf16x8 Bh = *(const bf16x8*)&wfr[(size_t)((24 + ks) * 64 + lane) * 8];
                #pragma unroll
                for (int mb = 0; mb < 4; ++mb) {
                    const bf16x8 Af = *(const bf16x8*)&actw[(mb * 16 + r16) * 72 + ks * 32 + q8];
                    acch[mb] = __builtin_amdgcn_mfma_f32_16x16x32_bf16(Af, Bh, acch[mb], 0, 0, 0);
                }
            }
            if (r16 < 3) {
                __half* dst = (r16 == 0) ? scr : (r16 == 1) ? scg : scb;
                const int jb = j * 256 + wave * 64;
                #pragma unroll
                for (int mb = 0; mb < 4; ++mb) {
                    #pragma unroll
                    for (int r = 0; r < 4; ++r) {
                        const int samp = mb * 16 + q4 + r;
                        dst[jb + samp] = __float2half(1.f / (1.f + __expf(-acch[mb][r])));
                    }
                }
            }
        }
    }
    __syncthreads();

    {
        float c0 = lgl[4*t + 0];
        float c1 = c0 + lgl[4*t + 1];
        float c2 = c1 + lgl[4*t + 2];
        float c3 = c2 + lgl[4*t + 3];
        lgl[4*t + 0] = c0; lgl[4*t + 1] = c1;
        lgl[4*t + 2] = c2; lgl[4*t + 3] = c3;
        aux[t] = c3;
    }
    __syncthreads();
    for (int off = 1; off < 256; off <<= 1) {
        const float v = (t >= off) ? aux[t - off] : 0.f;
        __syncthreads();
        aux[t] += v;
        __syncthreads();
    }
    const float total = aux[255];

    float r0 = 0.f, r1 = 0.f, r2 = 0.f;
    #pragma unroll
    for (int j = 0; j < 4; ++j) {
        const int s = j * 256 + t;
        const float a = __half2float(salpha[s]);
        if (s < N_SAMPLES && a > 0.f) {
            float G;
            if (s == 0) G = 0.f;
            else {
                const int m = s - 1;
                G = lgl[m] + (((m >> 2) > 0) ? aux[(m >> 2) - 1] : 0.f);
            }
            const float T = __expf(G);
            const float w = a * T;
            r0 = fmaf(w, __half2float(scr[s]), r0);
            r1 = fmaf(w, __half2float(scg[s]), r1);
            r2 = fmaf(w, __half2float(scb[s]), r2);
        }
    }
    #pragma unroll
    for (int off = 32; off > 0; off >>= 1) {
        r0 += __shfl_down(r0, off, 64);
        r1 += __shfl_down(r1, off, 64);
        r2 += __shfl_down(r2, off, 64);
    }
    if ((t & 63) == 0) {
        red[wave * 3 + 0] = r0; red[wave * 3 + 1] = r1; red[wave * 3 + 2] = r2;
    }
    __syncthreads();
    if (t == 0) {
        const float Tf = __expf(total);
        out[ray * 3 + 0] = red[0] + red[3] + red[6] + red[9]  + Tf;
        out[ray * 3 + 1] = red[1] + red[4] + red[7] + red[10] + Tf;
        out[ray * 3 + 2] = red[2] + red[5] + red[8] + red[11] + Tf;
    }
}

extern "C" void kernel_launch(void* const* d_in, const int* in_sizes, int n_in,
                              void* d_out, int out_size, void* d_ws, size_t ws_size,
                              hipStream_t stream) {
    (void)in_sizes; (void)n_in; (void)out_size;
    const float* ro    = (const float*)d_in[0];
    const float* rd    = (const float*)d_in[1];
    const float* vd    = (const float*)d_in[2];
    const float* grid  = (const float*)d_in[3];
    const float* sobel = (const float*)d_in[4];
    const float* w0 = (const float*)d_in[5];
    const float* b0 = (const float*)d_in[6];
    const float* w1 = (const float*)d_in[7];
    const float* b1 = (const float*)d_in[8];
    const float* w2 = (const float*)d_in[9];
    const float* b2 = (const float*)d_in[10];
    const float* w3 = (const float*)d_in[11];
    const float* b3 = (const float*)d_in[12];

    const size_t NRM_BYTES = (size_t)V3 * 16;            // 32 MB
    const size_t LAT_BYTES = (size_t)V3 * 32;            // 64 MB
    const size_t WFR_BYTES = 26 * 64 * 8 * 2;            // 26,624 B
    float4* nrm4 = (float4*)d_ws;
    const bool packed = (ws_size >= NRM_BYTES + LAT_BYTES + WFR_BYTES);
    unsigned short* latp = (unsigned short*)((char*)d_ws + NRM_BYTES);
    unsigned short* wfr  = packed
        ? (unsigned short*)((char*)d_ws + NRM_BYTES + LAT_BYTES)
        : (unsigned short*)((char*)d_ws + NRM_BYTES);

    if (packed) {
        prep_kernel<true><<<128 * 16, 256, 0, stream>>>(grid, sobel, nrm4, latp,
                                                        w0, w1, w2, w3, wfr);
        raymarch_kernel<true><<<N_RAYS, 256, 0, stream>>>(ro, rd, vd, grid, nrm4, latp, wfr,
                                                          b0, b1, b2, b3, (float*)d_out);
    } else {
        prep_kernel<false><<<128 * 16, 256, 0, stream>>>(grid, sobel, nrm4, latp,
                                                         w0, w1, w2, w3, wfr);
        raymarch_kernel<false><<<N_RAYS, 256, 0, stream>>>(ro, rd, vd, grid, nrm4, latp, wfr,
                                                           b0, b1, b2, b3, (float*)d_out);
    }
}